// Round 6
// baseline (189.972 us; speedup 1.0000x reference)
//
#include <hip/hip_runtime.h>
#include <hip/hip_bf16.h>
#include <math.h>

#define B_DIM 8192
#define IN_F  1024
#define OUT_F 1024
#define NSTEP 160                    // 32 g-groups x 5 slabs (K=5120)

typedef unsigned short u16;
typedef unsigned int u32;
typedef __attribute__((ext_vector_type(8))) short bf16x8;
typedef __attribute__((ext_vector_type(8))) unsigned short u16x8;
typedef __attribute__((ext_vector_type(4))) float f32x4;

__device__ __forceinline__ u16 f2bf(float v) {
    u32 u = __float_as_uint(v);
    return (u16)((u + 0x7FFFu + ((u >> 16) & 1u)) >> 16);
}

__device__ __forceinline__ u32 cvt_pk(float lo, float hi) {
    u32 r;
    asm("v_cvt_pk_bf16_f32 %0, %1, %2" : "=v"(r) : "v"(lo), "v"(hi));
    return r;
}

// ---------------------------------------------------------------------------
// B image, ordered by GEMM step t = g*5 + s  (g = k-octet group 0..31):
//   s=0: bf16(base_weight) cols g*32..g*32+31
//   s=1..4: bf16(sw_s - sw_{s-1}) same cols.
// Tile byte = ((p*160 + g*5 + s)*8192) + sn*1024 + lane*16,
// lane -> (fc=lane&15 col-in-subtile, q=lane>>4 k-octet). Every GEMM B-frag
// load is one contiguous dwordx4 per lane; B pointer advances 8192/step.
// ---------------------------------------------------------------------------
__global__ __launch_bounds__(256) void pack_B_kernel(
    const float* __restrict__ sw, const float* __restrict__ bw,
    char* __restrict__ Bt)
{
    int gid  = blockIdx.x * 256 + threadIdx.x;      // 131072 threads
    int lane = gid & 63;
    int wav  = gid >> 6;                            // 2048 waves
    int g    = wav & 31;
    int sn   = (wav >> 5) & 7;
    int p    = wav >> 8;                            // 0..7
    int fc   = lane & 15;
    int q    = lane >> 4;

    int o  = p * 128 + sn * 16 + fc;
    int i0 = g * 32 + q * 8;

    size_t tb = ((size_t)(p * 160 + g * 5)) * 8192
              + (size_t)sn * 1024 + (size_t)lane * 16;

    const float* bwr = bw + (size_t)o * IN_F + i0;
    float4 b0 = *(const float4*)bwr;
    float4 b1 = *(const float4*)(bwr + 4);
    float v[8] = {b0.x, b0.y, b0.z, b0.w, b1.x, b1.y, b1.z, b1.w};
    u16x8 s0;
    #pragma unroll
    for (int j = 0; j < 8; ++j) s0[j] = f2bf(v[j]);
    *(u16x8*)(Bt + tb) = s0;                        // s = 0

    float c[8][5];
    #pragma unroll
    for (int j = 0; j < 8; ++j) {
        const float* swr = sw + ((size_t)o * IN_F + i0 + j) * 8;
        float4 lo = *(const float4*)swr;
        float4 hi = *(const float4*)(swr + 4);
        c[j][0] = lo.x; c[j][1] = lo.y; c[j][2] = lo.z;
        c[j][3] = lo.w; c[j][4] = hi.x;
    }
    #pragma unroll
    for (int s = 1; s < 5; ++s) {
        u16x8 d;
        #pragma unroll
        for (int j = 0; j < 8; ++j) d[j] = f2bf(c[j][s] - c[j][s - 1]);
        *(u16x8*)(Bt + tb + (size_t)s * 8192) = d;
    }
}

// ---------------------------------------------------------------------------
// bias[o] = sum_i sw[o,i,0]; plus 4 x-space step thresholds: smallest f32 T
// with (x >= T) <=> ((double)x > atanh(midpoint(grid[s], prevfloat(grid[s])))),
// replicating a correctly-rounded tanh's interval comparisons.
// ---------------------------------------------------------------------------
__global__ __launch_bounds__(256) void bias_thresh_kernel(
    const float* __restrict__ sw, const float* __restrict__ grid,
    float* __restrict__ biasT)
{
    int o    = blockIdx.x * 4 + (threadIdx.x >> 6);
    int lane = threadIdx.x & 63;
    float s = 0.f;
    #pragma unroll
    for (int j = 0; j < 16; ++j)
        s += sw[((size_t)o * IN_F + j * 64 + lane) * 8];
    #pragma unroll
    for (int off = 32; off; off >>= 1)
        s += __shfl_down(s, off);
    if (lane == 0) biasT[o] = s;

    if (blockIdx.x == 0 && threadIdx.x == 0) {
        #pragma unroll
        for (int k = 0; k < 4; ++k) {
            float gv = grid[k + 1];                 // -0.6, -0.2, 0.2, 0.6
            float below = nextafterf(gv, -2.0f);
            double mid = 0.5 * ((double)gv + (double)below);
            double t = atanh(mid);
            float Tf = (float)t;
            if (!((double)Tf > t)) Tf = nextafterf(Tf, 3.0f);
            biasT[1024 + k] = Tf;
        }
    }
}

// ---------------------------------------------------------------------------
// Fused GEMM: C = [bf16(x) | 1[x>=T_s]] @ B^T + bias. No LDS, no barriers.
// 512 blocks x 512 threads (8 waves, 2x4); wave = 32x64 out = 2x4 frags.
// bcol = bid&7 == XCD -> per-XCD B footprint 1.25 MB (L2-resident).
// x and B double-buffered in registers; acc initialized with bias.
// ---------------------------------------------------------------------------
__device__ __forceinline__ void load_x(const float* xb, int g, float xg[2][8]) {
    #pragma unroll
    for (int m = 0; m < 2; ++m) {
        const float* p = xb + (size_t)m * 16 * IN_F + g * 32;
        float4 a = *(const float4*)p;
        float4 b = *(const float4*)(p + 4);
        xg[m][0] = a.x; xg[m][1] = a.y; xg[m][2] = a.z; xg[m][3] = a.w;
        xg[m][4] = b.x; xg[m][5] = b.y; xg[m][6] = b.z; xg[m][7] = b.w;
    }
}

__device__ __forceinline__ void load_b(const char* p, bf16x8 bb[4]) {
    bb[0] = *(const bf16x8*)(p);
    bb[1] = *(const bf16x8*)(p + 1024);
    bb[2] = *(const bf16x8*)(p + 2048);
    bb[3] = *(const bf16x8*)(p + 3072);
}

template <bool CVT>
__device__ __forceinline__ void do_step(const float xg[2][8], float T,
                                        const bf16x8 bb[4], f32x4 acc[2][4]) {
    bf16x8 af[2];
    #pragma unroll
    for (int m = 0; m < 2; ++m) {
        union { u32 u[4]; bf16x8 v; } t;
        #pragma unroll
        for (int p = 0; p < 4; ++p) {
            float lo, hi;
            if constexpr (CVT) {
                lo = xg[m][2 * p];
                hi = xg[m][2 * p + 1];
            } else {
                lo = xg[m][2 * p]     >= T ? 1.0f : 0.0f;
                hi = xg[m][2 * p + 1] >= T ? 1.0f : 0.0f;
            }
            t.u[p] = cvt_pk(lo, hi);
        }
        af[m] = t.v;
    }
    __builtin_amdgcn_s_setprio(1);
    #pragma unroll
    for (int m = 0; m < 2; ++m)
        #pragma unroll
        for (int n = 0; n < 4; ++n)
            acc[m][n] = __builtin_amdgcn_mfma_f32_16x16x32_bf16(
                af[m], bb[n], acc[m][n], 0, 0, 0);
    __builtin_amdgcn_s_setprio(0);
}

__global__ __launch_bounds__(512, 4) void gemm_kernel(
    const float* __restrict__ x, const char* __restrict__ Bt,
    const float* __restrict__ biasT, float* __restrict__ C)
{
    int tid = threadIdx.x;
    int bid = blockIdx.x;                           // 0..511

    int bcol = bid & 7;                             // == XCD (round-robin)
    int brow = bid >> 3;                            // 0..63

    int lane = tid & 63;
    int w    = tid >> 6;                            // 0..7
    int wr   = w >> 1;                              // 0..3 (32-row strip)
    int wc   = w & 1;                               // 0..1 (64-col half)
    int fr   = lane & 15;
    int q    = lane >> 4;

    float T1 = biasT[1024], T2 = biasT[1025], T3 = biasT[1026], T4 = biasT[1027];

    const float* xb = x + (size_t)(brow * 128 + wr * 32 + fr) * IN_F + q * 8;
    const char*  Bw = Bt + (size_t)bcol * NSTEP * 8192
                    + (size_t)(wc * 4) * 1024 + (size_t)lane * 16;

    int ccol0 = bcol * 128 + wc * 64 + fr;

    f32x4 acc[2][4];
    #pragma unroll
    for (int n = 0; n < 4; ++n) {
        float bv = biasT[ccol0 + n * 16];
        #pragma unroll
        for (int m = 0; m < 2; ++m)
            #pragma unroll
            for (int j = 0; j < 4; ++j)
                acc[m][n][j] = bv;
    }

    float xA[2][8], xB[2][8];
    bf16x8 bb0[4], bb1[4];
    load_x(xb, 0, xA);
    load_b(Bw,        bb0);
    load_b(Bw + 8192, bb1);

    #pragma unroll 1
    for (int gg = 0; gg < 16; ++gg) {
        const char* Bp = Bw + (size_t)(gg * 10) * 8192;
        // g = 2*gg (xA), slabs s=0..4; prefetch x(2*gg+1) and B(t+2) as we go.
        do_step<true >(xA, 0.f, bb0, acc); load_b(Bp + 2 * 8192, bb0);
        load_x(xb, 2 * gg + 1, xB);
        do_step<false>(xA, T1,  bb1, acc); load_b(Bp + 3 * 8192, bb1);
        do_step<false>(xA, T2,  bb0, acc); load_b(Bp + 4 * 8192, bb0);
        do_step<false>(xA, T3,  bb1, acc); load_b(Bp + 5 * 8192, bb1);
        do_step<false>(xA, T4,  bb0, acc); load_b(Bp + 6 * 8192, bb0);
        // g = 2*gg+1 (xB)
        do_step<true >(xB, 0.f, bb1, acc); load_b(Bp + 7 * 8192, bb1);
        if (gg < 15) load_x(xb, 2 * gg + 2, xA);
        do_step<false>(xB, T1,  bb0, acc); load_b(Bp + 8 * 8192, bb0);
        do_step<false>(xB, T2,  bb1, acc); load_b(Bp + 9 * 8192, bb1);
        do_step<false>(xB, T3,  bb0, acc);
        if (gg < 15) load_b(Bp + 10 * 8192, bb0);
        do_step<false>(xB, T4,  bb1, acc);
        if (gg < 15) load_b(Bp + 11 * 8192, bb1);
    }

    // epilogue: C/D layout col = lane&15, row = (lane>>4)*4 + reg (bias in acc)
    int crow0 = brow * 128 + wr * 32 + (q << 2);
    #pragma unroll
    for (int m = 0; m < 2; ++m)
        #pragma unroll
        for (int j = 0; j < 4; ++j) {
            size_t r = (size_t)(crow0 + m * 16 + j);
            float* cp = C + r * OUT_F + ccol0;
            #pragma unroll
            for (int n = 0; n < 4; ++n)
                cp[n * 16] = acc[m][n][j];
        }
}

// Fallback signal if workspace is too small: absmax will read ~12345.
__global__ void sentinel_kernel(float* out, int n) {
    int i = blockIdx.x * 256 + threadIdx.x;
    if (i < n) out[i] = (i == 0) ? 12345.0f : 0.0f;
}

extern "C" void kernel_launch(void* const* d_in, const int* in_sizes, int n_in,
                              void* d_out, int out_size, void* d_ws, size_t ws_size,
                              hipStream_t stream) {
    const float* x    = (const float*)d_in[0];
    const float* sw   = (const float*)d_in[1];
    const float* bw   = (const float*)d_in[2];
    const float* grid = (const float*)d_in[3];
    float* out = (float*)d_out;

    const size_t B_bytes = (size_t)8 * NSTEP * 8192;    // 10,485,760
    const size_t bias_bytes = (1024 + 4) * sizeof(float);
    if (ws_size < B_bytes + bias_bytes) {
        sentinel_kernel<<<(out_size + 255) / 256, 256, 0, stream>>>(out, out_size);
        return;
    }

    char*  Bt    = (char*)d_ws;
    float* biasT = (float*)((char*)d_ws + B_bytes);

    bias_thresh_kernel<<<256, 256, 0, stream>>>(sw, grid, biasT);
    pack_B_kernel<<<512, 256, 0, stream>>>(sw, bw, Bt);
    gemm_kernel<<<512, 512, 0, stream>>>(x, Bt, biasT, out);
}

// Round 7
// 140.924 us; speedup vs baseline: 1.3481x; 1.3481x over previous
//
#include <hip/hip_runtime.h>
#include <hip/hip_bf16.h>
#include <math.h>

#define B_DIM 8192
#define IN_F  1024
#define OUT_F 1024
#define NSTEP 160                    // 32 g-groups x 5 slabs (K=5120)
#define BTILE 8192                   // one B step-tile: 128 cols x 32 k x 2B

typedef unsigned short u16;
typedef unsigned int u32;
typedef __attribute__((ext_vector_type(8))) short bf16x8;
typedef __attribute__((ext_vector_type(8))) unsigned short u16x8;
typedef __attribute__((ext_vector_type(4))) float f32x4;

#define GLOBAL_AS __attribute__((address_space(1)))
#define LDS_AS    __attribute__((address_space(3)))

__device__ __forceinline__ void gload16(const void* g, void* l) {
    __builtin_amdgcn_global_load_lds((const GLOBAL_AS unsigned int*)g,
                                     (LDS_AS unsigned int*)l, 16, 0, 0);
}

__device__ __forceinline__ u16 f2bf(float v) {
    u32 u = __float_as_uint(v);
    return (u16)((u + 0x7FFFu + ((u >> 16) & 1u)) >> 16);
}

__device__ __forceinline__ u32 cvt_pk(float lo, float hi) {
    u32 r;
    asm("v_cvt_pk_bf16_f32 %0, %1, %2" : "=v"(r) : "v"(lo), "v"(hi));
    return r;
}

// ---------------------------------------------------------------------------
// B image, ordered by GEMM step t = g*5 + s  (g = k-octet group 0..31):
//   s=0: bf16(base_weight) cols g*32..g*32+31
//   s=1..4: bf16(sw_s - sw_{s-1}) same cols.
// Tile byte = ((p*160 + g*5 + s)*8192) + sn*1024 + lane*16. Every GEMM-side
// access (gload_lds dst/src and ds_read_b128) is base + lane*16.
// ---------------------------------------------------------------------------
__global__ __launch_bounds__(256) void pack_B_kernel(
    const float* __restrict__ sw, const float* __restrict__ bw,
    char* __restrict__ Bt)
{
    int gid  = blockIdx.x * 256 + threadIdx.x;      // 131072 threads
    int lane = gid & 63;
    int wav  = gid >> 6;                            // 2048 waves
    int g    = wav & 31;
    int sn   = (wav >> 5) & 7;
    int p    = wav >> 8;                            // 0..7
    int fc   = lane & 15;
    int q    = lane >> 4;

    int o  = p * 128 + sn * 16 + fc;
    int i0 = g * 32 + q * 8;

    size_t tb = ((size_t)(p * 160 + g * 5)) * 8192
              + (size_t)sn * 1024 + (size_t)lane * 16;

    const float* bwr = bw + (size_t)o * IN_F + i0;
    float4 b0 = *(const float4*)bwr;
    float4 b1 = *(const float4*)(bwr + 4);
    float v[8] = {b0.x, b0.y, b0.z, b0.w, b1.x, b1.y, b1.z, b1.w};
    u16x8 s0;
    #pragma unroll
    for (int j = 0; j < 8; ++j) s0[j] = f2bf(v[j]);
    *(u16x8*)(Bt + tb) = s0;                        // s = 0

    float c[8][5];
    #pragma unroll
    for (int j = 0; j < 8; ++j) {
        const float* swr = sw + ((size_t)o * IN_F + i0 + j) * 8;
        float4 lo = *(const float4*)swr;
        float4 hi = *(const float4*)(swr + 4);
        c[j][0] = lo.x; c[j][1] = lo.y; c[j][2] = lo.z;
        c[j][3] = lo.w; c[j][4] = hi.x;
    }
    #pragma unroll
    for (int s = 1; s < 5; ++s) {
        u16x8 d;
        #pragma unroll
        for (int j = 0; j < 8; ++j) d[j] = f2bf(c[j][s] - c[j][s - 1]);
        *(u16x8*)(Bt + tb + (size_t)s * 8192) = d;
    }
}

// ---------------------------------------------------------------------------
// bias[o] = sum_i sw[o,i,0]; plus 4 x-space step thresholds: smallest f32 T
// with (x >= T) <=> ((double)x > atanh(midpoint(grid[s], prevfloat(grid[s])))),
// replicating a correctly-rounded tanh's interval comparisons.
// ---------------------------------------------------------------------------
__global__ __launch_bounds__(256) void bias_thresh_kernel(
    const float* __restrict__ sw, const float* __restrict__ grid,
    float* __restrict__ biasT)
{
    int o    = blockIdx.x * 4 + (threadIdx.x >> 6);
    int lane = threadIdx.x & 63;
    float s = 0.f;
    #pragma unroll
    for (int j = 0; j < 16; ++j)
        s += sw[((size_t)o * IN_F + j * 64 + lane) * 8];
    #pragma unroll
    for (int off = 32; off; off >>= 1)
        s += __shfl_down(s, off);
    if (lane == 0) biasT[o] = s;

    if (blockIdx.x == 0 && threadIdx.x == 0) {
        #pragma unroll
        for (int k = 0; k < 4; ++k) {
            float gv = grid[k + 1];                 // -0.6, -0.2, 0.2, 0.6
            float below = nextafterf(gv, -2.0f);
            double mid = 0.5 * ((double)gv + (double)below);
            double t = atanh(mid);
            float Tf = (float)t;
            if (!((double)Tf > t)) Tf = nextafterf(Tf, 3.0f);
            biasT[1024 + k] = Tf;
        }
    }
}

// ---------------------------------------------------------------------------
// Fused GEMM: C = [bf16(x) | 1[x>=T_s]] @ B^T + bias.
// A built in registers from x (no pack_A, no A memory). B staged through a
// 4-deep LDS ring with global_load_lds + counted vmcnt {12,12,12,4,4}:
// B loads stay in flight across barriers, never drained to 0 in the loop.
// 512 blocks x 256 threads (4 waves 2x2); wave = 64x64 out = 4x4 frags.
// bcol = bid&7 == XCD -> per-XCD B panel 1.25 MB, L2-resident; x via L3.
// ---------------------------------------------------------------------------
__device__ __forceinline__ void load_x(const float* xb, int g, float xc[4][8]) {
    #pragma unroll
    for (int m = 0; m < 4; ++m) {
        const float* p = xb + (size_t)m * 16 * IN_F + g * 32;
        float4 a = *(const float4*)p;
        float4 b = *(const float4*)(p + 4);
        xc[m][0] = a.x; xc[m][1] = a.y; xc[m][2] = a.z; xc[m][3] = a.w;
        xc[m][4] = b.x; xc[m][5] = b.y; xc[m][6] = b.z; xc[m][7] = b.w;
    }
}

__device__ __forceinline__ void build_af_cvt(const float xc[4][8], bf16x8 af[4]) {
    #pragma unroll
    for (int m = 0; m < 4; ++m) {
        union { u32 u[4]; bf16x8 v; } t;
        #pragma unroll
        for (int p = 0; p < 4; ++p)
            t.u[p] = cvt_pk(xc[m][2 * p], xc[m][2 * p + 1]);
        af[m] = t.v;
    }
}

__device__ __forceinline__ void build_af_ind(const float xc[4][8], float T,
                                             bf16x8 af[4]) {
    #pragma unroll
    for (int m = 0; m < 4; ++m) {
        union { u32 u[4]; bf16x8 v; } t;
        #pragma unroll
        for (int p = 0; p < 4; ++p)
            t.u[p] = cvt_pk(xc[m][2 * p]     >= T ? 1.0f : 0.0f,
                            xc[m][2 * p + 1] >= T ? 1.0f : 0.0f);
        af[m] = t.v;
    }
}

__device__ __forceinline__ void mfma_step(const char* slotbase, int wc, int lane,
                                          const bf16x8 af[4], f32x4 acc[4][4]) {
    bf16x8 bf[4];
    #pragma unroll
    for (int n = 0; n < 4; ++n)
        bf[n] = *(const bf16x8*)(slotbase + (wc * 4 + n) * 1024 + lane * 16);
    __builtin_amdgcn_s_setprio(1);
    #pragma unroll
    for (int m = 0; m < 4; ++m)
        #pragma unroll
        for (int n = 0; n < 4; ++n)
            acc[m][n] = __builtin_amdgcn_mfma_f32_16x16x32_bf16(
                af[m], bf[n], acc[m][n], 0, 0, 0);
    __builtin_amdgcn_s_setprio(0);
}

#define WAITV(N) asm volatile("s_waitcnt vmcnt(" #N ")" ::: "memory")

__global__ __launch_bounds__(256, 2) void gemm_kernel(
    const float* __restrict__ x, const char* __restrict__ Bt,
    const float* __restrict__ biasT, float* __restrict__ C)
{
    __shared__ __align__(16) char lds[4 * BTILE];   // B-only ring, 32 KB

    int tid = threadIdx.x;
    int bid = blockIdx.x;                           // 0..511

    int bcol = bid & 7;                             // == XCD (round-robin)
    int brow = bid >> 3;                            // 0..63

    int lane = tid & 63;
    int w    = tid >> 6;
    int wr   = w >> 1;
    int wc   = w & 1;
    int fr   = lane & 15;
    int q    = lane >> 4;

    float T1 = biasT[1024], T2 = biasT[1025], T3 = biasT[1026], T4 = biasT[1027];

    const float* xb  = x + (size_t)(brow * 128 + wr * 64 + fr) * IN_F + q * 8;
    const char* ssrc = Bt + (size_t)bcol * NSTEP * BTILE + (size_t)tid * 16;
    char*       sdst = lds + (size_t)tid * 16;

    int ccol0 = bcol * 128 + wc * 64 + fr;

    f32x4 acc[4][4];
    #pragma unroll
    for (int n = 0; n < 4; ++n) {
        float bv = biasT[ccol0 + n * 16];
        #pragma unroll
        for (int m = 0; m < 4; ++m)
            #pragma unroll
            for (int j = 0; j < 4; ++j)
                acc[m][n][j] = bv;
    }

    // stage tile t into ring slot (2 x 16B per thread, linear)
    #define STAGE(T, SLOT) do {                                              \
        gload16(ssrc + (size_t)(T) * BTILE,        sdst + (SLOT) * BTILE);   \
        gload16(ssrc + (size_t)(T) * BTILE + 4096, sdst + (SLOT) * BTILE + 4096); \
    } while (0)

    float xc[4][8];
    bf16x8 af[4];

    // prologue: S(0),S(1),x(0),S(2) — matches steady-state queue pattern
    STAGE(0, 0);
    STAGE(1, 1);
    load_x(xb, 0, xc);
    STAGE(2, 2);

    #pragma unroll 1
    for (int g = 0; g < 31; ++g) {
        int t = 5 * g;
        // s=0 (slab 0: bf16(x))
        WAITV(12); __builtin_amdgcn_s_barrier();
        STAGE(t + 3, (g + 3) & 3);
        WAITV(2);                                   // x(g) guaranteed done
        __builtin_amdgcn_sched_barrier(0);
        build_af_cvt(xc, af);
        mfma_step(lds + (g & 3) * BTILE, wc, lane, af, acc);
        // s=1
        WAITV(12); __builtin_amdgcn_s_barrier();
        STAGE(t + 4, (g + 4) & 3);
        build_af_ind(xc, T1, af);
        mfma_step(lds + ((g + 1) & 3) * BTILE, wc, lane, af, acc);
        // s=2
        WAITV(12); __builtin_amdgcn_s_barrier();
        STAGE(t + 5, (g + 5) & 3);
        build_af_ind(xc, T2, af);
        mfma_step(lds + ((g + 2) & 3) * BTILE, wc, lane, af, acc);
        // s=3
        WAITV(4); __builtin_amdgcn_s_barrier();
        STAGE(t + 6, (g + 6) & 3);
        build_af_ind(xc, T3, af);
        mfma_step(lds + ((g + 3) & 3) * BTILE, wc, lane, af, acc);
        // s=4: build af from xc FIRST, then reload xc for g+1 (WAR)
        WAITV(4); __builtin_amdgcn_s_barrier();
        STAGE(t + 7, (g + 7) & 3);
        build_af_ind(xc, T4, af);
        load_x(xb, g + 1, xc);
        mfma_step(lds + ((g + 4) & 3) * BTILE, wc, lane, af, acc);
    }

    // tail g=31: tiles 155..159 (slots 3,0,1,2,3); stages 158,159 only
    WAITV(12); __builtin_amdgcn_s_barrier();
    STAGE(158, 2);
    WAITV(2);
    __builtin_amdgcn_sched_barrier(0);
    build_af_cvt(xc, af);
    mfma_step(lds + 3 * BTILE, wc, lane, af, acc);

    WAITV(12); __builtin_amdgcn_s_barrier();
    STAGE(159, 3);
    build_af_ind(xc, T1, af);
    mfma_step(lds + 0 * BTILE, wc, lane, af, acc);

    WAITV(4); __builtin_amdgcn_s_barrier();
    build_af_ind(xc, T2, af);
    mfma_step(lds + 1 * BTILE, wc, lane, af, acc);

    WAITV(2); __builtin_amdgcn_s_barrier();
    build_af_ind(xc, T3, af);
    mfma_step(lds + 2 * BTILE, wc, lane, af, acc);

    WAITV(0); __builtin_amdgcn_s_barrier();
    build_af_ind(xc, T4, af);
    mfma_step(lds + 3 * BTILE, wc, lane, af, acc);

    // epilogue: C/D layout col = lane&15, row = (lane>>4)*4 + reg (bias in acc)
    int crow0 = brow * 128 + wr * 64 + (q << 2);
    #pragma unroll
    for (int m = 0; m < 4; ++m)
        #pragma unroll
        for (int j = 0; j < 4; ++j) {
            size_t r = (size_t)(crow0 + m * 16 + j);
            float* cp = C + r * OUT_F + ccol0;
            #pragma unroll
            for (int n = 0; n < 4; ++n)
                cp[n * 16] = acc[m][n][j];
        }
    #undef STAGE
}

// Fallback signal if workspace is too small: absmax will read ~12345.
__global__ void sentinel_kernel(float* out, int n) {
    int i = blockIdx.x * 256 + threadIdx.x;
    if (i < n) out[i] = (i == 0) ? 12345.0f : 0.0f;
}

extern "C" void kernel_launch(void* const* d_in, const int* in_sizes, int n_in,
                              void* d_out, int out_size, void* d_ws, size_t ws_size,
                              hipStream_t stream) {
    const float* x    = (const float*)d_in[0];
    const float* sw   = (const float*)d_in[1];
    const float* bw   = (const float*)d_in[2];
    const float* grid = (const float*)d_in[3];
    float* out = (float*)d_out;

    const size_t B_bytes = (size_t)8 * NSTEP * BTILE;   // 10,485,760
    const size_t bias_bytes = (1024 + 4) * sizeof(float);
    if (ws_size < B_bytes + bias_bytes) {
        sentinel_kernel<<<(out_size + 255) / 256, 256, 0, stream>>>(out, out_size);
        return;
    }

    char*  Bt    = (char*)d_ws;
    float* biasT = (float*)((char*)d_ws + B_bytes);

    bias_thresh_kernel<<<256, 256, 0, stream>>>(sw, grid, biasT);
    pack_B_kernel<<<512, 256, 0, stream>>>(sw, bw, Bt);
    gemm_kernel<<<512, 256, 0, stream>>>(x, Bt, biasT, out);
}

// Round 8
// 124.407 us; speedup vs baseline: 1.5270x; 1.1328x over previous
//
#include <hip/hip_runtime.h>
#include <hip/hip_bf16.h>
#include <math.h>

#define B_DIM 8192
#define IN_F  1024
#define OUT_F 1024
#define NSTEP 160                    // 32 g-groups x 5 slabs (K=5120)
#define BTILE 8192                   // one B step-tile: 128 cols x 32 k x 2B
#define GBYTES (5 * BTILE)           // one g-group of B tiles: 40 KB

typedef unsigned short u16;
typedef unsigned int u32;
typedef __attribute__((ext_vector_type(8))) short bf16x8;
typedef __attribute__((ext_vector_type(8))) unsigned short u16x8;
typedef __attribute__((ext_vector_type(4))) float f32x4;

#define GLOBAL_AS __attribute__((address_space(1)))
#define LDS_AS    __attribute__((address_space(3)))

__device__ __forceinline__ void gload16(const void* g, void* l) {
    __builtin_amdgcn_global_load_lds((const GLOBAL_AS unsigned int*)g,
                                     (LDS_AS unsigned int*)l, 16, 0, 0);
}

__device__ __forceinline__ u16 f2bf(float v) {
    u32 u = __float_as_uint(v);
    return (u16)((u + 0x7FFFu + ((u >> 16) & 1u)) >> 16);
}

__device__ __forceinline__ u32 cvt_pk(float lo, float hi) {
    u32 r;
    asm("v_cvt_pk_bf16_f32 %0, %1, %2" : "=v"(r) : "v"(lo), "v"(hi));
    return r;
}

// ---------------------------------------------------------------------------
// B image, ordered by GEMM step t = g*5 + s  (g = k-octet group 0..31):
//   s=0: bf16(base_weight) cols g*32..g*32+31
//   s=1..4: bf16(sw_s - sw_{s-1}) same cols.
// Tile byte = ((p*160 + g*5 + s)*8192) + sn*1024 + lane*16. One g-group's
// 5 tiles are 40 KB contiguous -> staged with 10 linear gload16/thread.
// ---------------------------------------------------------------------------
__global__ __launch_bounds__(256) void pack_B_kernel(
    const float* __restrict__ sw, const float* __restrict__ bw,
    char* __restrict__ Bt)
{
    int gid  = blockIdx.x * 256 + threadIdx.x;      // 131072 threads
    int lane = gid & 63;
    int wav  = gid >> 6;                            // 2048 waves
    int g    = wav & 31;
    int sn   = (wav >> 5) & 7;
    int p    = wav >> 8;                            // 0..7
    int fc   = lane & 15;
    int q    = lane >> 4;

    int o  = p * 128 + sn * 16 + fc;
    int i0 = g * 32 + q * 8;

    size_t tb = ((size_t)(p * 160 + g * 5)) * 8192
              + (size_t)sn * 1024 + (size_t)lane * 16;

    const float* bwr = bw + (size_t)o * IN_F + i0;
    float4 b0 = *(const float4*)bwr;
    float4 b1 = *(const float4*)(bwr + 4);
    float v[8] = {b0.x, b0.y, b0.z, b0.w, b1.x, b1.y, b1.z, b1.w};
    u16x8 s0;
    #pragma unroll
    for (int j = 0; j < 8; ++j) s0[j] = f2bf(v[j]);
    *(u16x8*)(Bt + tb) = s0;                        // s = 0

    float c[8][5];
    #pragma unroll
    for (int j = 0; j < 8; ++j) {
        const float* swr = sw + ((size_t)o * IN_F + i0 + j) * 8;
        float4 lo = *(const float4*)swr;
        float4 hi = *(const float4*)(swr + 4);
        c[j][0] = lo.x; c[j][1] = lo.y; c[j][2] = lo.z;
        c[j][3] = lo.w; c[j][4] = hi.x;
    }
    #pragma unroll
    for (int s = 1; s < 5; ++s) {
        u16x8 d;
        #pragma unroll
        for (int j = 0; j < 8; ++j) d[j] = f2bf(c[j][s] - c[j][s - 1]);
        *(u16x8*)(Bt + tb + (size_t)s * 8192) = d;
    }
}

// ---------------------------------------------------------------------------
// bias[o] = sum_i sw[o,i,0]; plus 4 x-space step thresholds: smallest f32 T
// with (x >= T) <=> ((double)x > atanh(midpoint(grid[s], prevfloat(grid[s])))),
// replicating a correctly-rounded tanh's interval comparisons.
// ---------------------------------------------------------------------------
__global__ __launch_bounds__(256) void bias_thresh_kernel(
    const float* __restrict__ sw, const float* __restrict__ grid,
    float* __restrict__ biasT)
{
    int o    = blockIdx.x * 4 + (threadIdx.x >> 6);
    int lane = threadIdx.x & 63;
    float s = 0.f;
    #pragma unroll
    for (int j = 0; j < 16; ++j)
        s += sw[((size_t)o * IN_F + j * 64 + lane) * 8];
    #pragma unroll
    for (int off = 32; off; off >>= 1)
        s += __shfl_down(s, off);
    if (lane == 0) biasT[o] = s;

    if (blockIdx.x == 0 && threadIdx.x == 0) {
        #pragma unroll
        for (int k = 0; k < 4; ++k) {
            float gv = grid[k + 1];                 // -0.6, -0.2, 0.2, 0.6
            float below = nextafterf(gv, -2.0f);
            double mid = 0.5 * ((double)gv + (double)below);
            double t = atanh(mid);
            float Tf = (float)t;
            if (!((double)Tf > t)) Tf = nextafterf(Tf, 3.0f);
            biasT[1024 + k] = Tf;
        }
    }
}

// ---------------------------------------------------------------------------
// Fused GEMM: C = [bf16(x) | 1[x>=T_s]] @ B^T + bias.
// One barrier per g-group (33 total): stage all 5 tiles of g+1, compute the
// 5 slabs barrier-free, vmcnt(8) (drains the 10 stage loads, leaves 8 x
// loads in flight), s_barrier. Wave phases staggered: each wave walks the
// 4 indicator slabs rotated by wave-id so VALU/MFMA/LDS pipes interleave.
// 512 blocks x 256 threads (4 waves 2x2); wave = 64x64 out = 4x4 frags.
// ---------------------------------------------------------------------------
__device__ __forceinline__ void load_x(const float* xb, int g, float xc[4][8]) {
    #pragma unroll
    for (int m = 0; m < 4; ++m) {
        const float* p = xb + (size_t)m * 16 * IN_F + g * 32;
        float4 a = *(const float4*)p;
        float4 b = *(const float4*)(p + 4);
        xc[m][0] = a.x; xc[m][1] = a.y; xc[m][2] = a.z; xc[m][3] = a.w;
        xc[m][4] = b.x; xc[m][5] = b.y; xc[m][6] = b.z; xc[m][7] = b.w;
    }
}

__device__ __forceinline__ void build_af_cvt(const float xc[4][8], bf16x8 af[4]) {
    #pragma unroll
    for (int m = 0; m < 4; ++m) {
        union { u32 u[4]; bf16x8 v; } t;
        #pragma unroll
        for (int p = 0; p < 4; ++p)
            t.u[p] = cvt_pk(xc[m][2 * p], xc[m][2 * p + 1]);
        af[m] = t.v;
    }
}

__device__ __forceinline__ void build_af_ind(const float xc[4][8], float T,
                                             bf16x8 af[4]) {
    #pragma unroll
    for (int m = 0; m < 4; ++m) {
        union { u32 u[4]; bf16x8 v; } t;
        #pragma unroll
        for (int p = 0; p < 4; ++p)
            t.u[p] = cvt_pk(xc[m][2 * p]     >= T ? 1.0f : 0.0f,
                            xc[m][2 * p + 1] >= T ? 1.0f : 0.0f);
        af[m] = t.v;
    }
}

__device__ __forceinline__ void mfma_step(const char* slotbase, int wc, int lane,
                                          const bf16x8 af[4], f32x4 acc[4][4]) {
    bf16x8 bf[4];
    #pragma unroll
    for (int n = 0; n < 4; ++n)
        bf[n] = *(const bf16x8*)(slotbase + (wc * 4 + n) * 1024 + lane * 16);
    __builtin_amdgcn_s_setprio(1);
    #pragma unroll
    for (int m = 0; m < 4; ++m)
        #pragma unroll
        for (int n = 0; n < 4; ++n)
            acc[m][n] = __builtin_amdgcn_mfma_f32_16x16x32_bf16(
                af[m], bf[n], acc[m][n], 0, 0, 0);
    __builtin_amdgcn_s_setprio(0);
}

#define WAITV(N) asm volatile("s_waitcnt vmcnt(" #N ")" ::: "memory")

__global__ __launch_bounds__(256, 2) void gemm_kernel(
    const float* __restrict__ x, const char* __restrict__ Bt,
    const float* __restrict__ biasT, float* __restrict__ C)
{
    __shared__ __align__(16) char lds[2 * GBYTES]; // 80 KB: 2 g-group buffers

    int tid = threadIdx.x;
    int bid = blockIdx.x;                           // 0..511

    int bcol = bid & 7;                             // == XCD (round-robin)
    int brow = bid >> 3;                            // 0..63

    int lane = tid & 63;
    int w    = tid >> 6;                            // 0..3
    int wr   = w >> 1;
    int wc   = w & 1;
    int fr   = lane & 15;
    int q    = lane >> 4;

    // thresholds, rotated left by wave-id (stagger); matching tile offsets
    float u0 = biasT[1024], u1 = biasT[1025], u2 = biasT[1026], u3 = biasT[1027];
    if (w & 1) { float t = u0; u0 = u1; u1 = u2; u2 = u3; u3 = t; }
    if (w & 2) { float t0 = u0, t1 = u1; u0 = u2; u1 = u3; u2 = t0; u3 = t1; }
    int o0 = (1 + ((0 + w) & 3)) * BTILE;
    int o1 = (1 + ((1 + w) & 3)) * BTILE;
    int o2 = (1 + ((2 + w) & 3)) * BTILE;
    int o3 = (1 + ((3 + w) & 3)) * BTILE;

    const float* xb  = x + (size_t)(brow * 128 + wr * 64 + fr) * IN_F + q * 8;
    const char* ssrc = Bt + (size_t)bcol * NSTEP * BTILE + (size_t)tid * 16;
    char*       sdst = lds + (size_t)tid * 16;

    int ccol0 = bcol * 128 + wc * 64 + fr;

    f32x4 acc[4][4];
    #pragma unroll
    for (int n = 0; n < 4; ++n) {
        float bv = biasT[ccol0 + n * 16];
        #pragma unroll
        for (int m = 0; m < 4; ++m)
            #pragma unroll
            for (int j = 0; j < 4; ++j)
                acc[m][n][j] = bv;
    }

    // stage all 5 tiles of g-group G into buffer BUF (10 x 16B per thread)
    #define STAGE_G(G, BUF) do {                                              \
        const char* _s = ssrc + (size_t)(5 * (G)) * BTILE;                    \
        char* _d = sdst + (size_t)(BUF) * GBYTES;                             \
        _Pragma("unroll")                                                     \
        for (int _t = 0; _t < 5; ++_t) {                                      \
            gload16(_s + _t * BTILE,        _d + _t * BTILE);                 \
            gload16(_s + _t * BTILE + 4096, _d + _t * BTILE + 4096);          \
        }                                                                     \
    } while (0)

    #define COMPUTE5(XC, BUF) do {                                            \
        const char* _b = lds + (size_t)(BUF) * GBYTES;                        \
        bf16x8 af[4];                                                         \
        build_af_cvt((XC), af);      mfma_step(_b,      wc, lane, af, acc);   \
        build_af_ind((XC), u0, af);  mfma_step(_b + o0, wc, lane, af, acc);   \
        build_af_ind((XC), u1, af);  mfma_step(_b + o1, wc, lane, af, acc);   \
        build_af_ind((XC), u2, af);  mfma_step(_b + o2, wc, lane, af, acc);   \
        build_af_ind((XC), u3, af);  mfma_step(_b + o3, wc, lane, af, acc);   \
    } while (0)

    float xA[4][8], xB[4][8];

    // prologue
    load_x(xb, 0, xA);
    STAGE_G(0, 0);
    WAITV(0);
    __builtin_amdgcn_s_barrier();

    #pragma unroll 1
    for (int gg = 0; gg < 15; ++gg) {
        int g = 2 * gg;
        // even g: consume xA, buffer g&1 = 0
        STAGE_G(g + 1, 1);
        __builtin_amdgcn_sched_barrier(0);          // pin: stages before x
        load_x(xb, g + 1, xB);
        __builtin_amdgcn_sched_barrier(0);          // pin: loads issued above
        COMPUTE5(xA, 0);
        WAITV(8);                                   // drain the 10 stage loads
        __builtin_amdgcn_s_barrier();
        // odd g: consume xB, buffer 1
        STAGE_G(g + 2, 0);
        __builtin_amdgcn_sched_barrier(0);
        load_x(xb, g + 2, xA);
        __builtin_amdgcn_sched_barrier(0);
        COMPUTE5(xB, 1);
        WAITV(8);
        __builtin_amdgcn_s_barrier();
    }
    // g=30: stage 31, load x31
    STAGE_G(31, 1);
    __builtin_amdgcn_sched_barrier(0);
    load_x(xb, 31, xB);
    __builtin_amdgcn_sched_barrier(0);
    COMPUTE5(xA, 0);
    WAITV(8);
    __builtin_amdgcn_s_barrier();
    // g=31: compute only
    COMPUTE5(xB, 1);

    // epilogue: C/D layout col = lane&15, row = (lane>>4)*4 + reg (bias in acc)
    int crow0 = brow * 128 + wr * 64 + (q << 2);
    #pragma unroll
    for (int m = 0; m < 4; ++m)
        #pragma unroll
        for (int j = 0; j < 4; ++j) {
            size_t r = (size_t)(crow0 + m * 16 + j);
            float* cp = C + r * OUT_F + ccol0;
            #pragma unroll
            for (int n = 0; n < 4; ++n)
                cp[n * 16] = acc[m][n][j];
        }
    #undef STAGE_G
    #undef COMPUTE5
}

// Fallback signal if workspace is too small: absmax will read ~12345.
__global__ void sentinel_kernel(float* out, int n) {
    int i = blockIdx.x * 256 + threadIdx.x;
    if (i < n) out[i] = (i == 0) ? 12345.0f : 0.0f;
}

extern "C" void kernel_launch(void* const* d_in, const int* in_sizes, int n_in,
                              void* d_out, int out_size, void* d_ws, size_t ws_size,
                              hipStream_t stream) {
    const float* x    = (const float*)d_in[0];
    const float* sw   = (const float*)d_in[1];
    const float* bw   = (const float*)d_in[2];
    const float* grid = (const float*)d_in[3];
    float* out = (float*)d_out;

    const size_t B_bytes = (size_t)8 * NSTEP * BTILE;   // 10,485,760
    const size_t bias_bytes = (1024 + 4) * sizeof(float);
    if (ws_size < B_bytes + bias_bytes) {
        sentinel_kernel<<<(out_size + 255) / 256, 256, 0, stream>>>(out, out_size);
        return;
    }

    char*  Bt    = (char*)d_ws;
    float* biasT = (float*)((char*)d_ws + B_bytes);

    bias_thresh_kernel<<<256, 256, 0, stream>>>(sw, grid, biasT);
    pack_B_kernel<<<512, 256, 0, stream>>>(sw, bw, Bt);
    gemm_kernel<<<512, 256, 0, stream>>>(x, Bt, biasT, out);
}